// Round 6
// baseline (144.260 us; speedup 1.0000x reference)
//
#include <hip/hip_runtime.h>
#include <hip/hip_fp16.h>

#define B_    4
#define C_    192
#define N_    8192
#define K_    16
#define O_    192
#define TWOC_ 384
#define BN_   (B_ * N_)

typedef __attribute__((ext_vector_type(8))) _Float16 half8;
typedef __attribute__((ext_vector_type(4))) _Float16 half4v;
typedef __attribute__((ext_vector_type(2))) _Float16 half2v;
typedef __attribute__((ext_vector_type(4))) float floatx4;
typedef __attribute__((ext_vector_type(4))) float fvec4;
typedef __attribute__((ext_vector_type(4))) int   ivec4;
typedef __attribute__((ext_vector_type(4))) unsigned int uvec4;
typedef __attribute__((ext_vector_type(2))) unsigned int uvec2;

// ---------------- K1: prep ----------------
// blocks 0..6143: 32x32 transpose tiles -> xt[b,n,c] fp16  AND  passthrough xc[b,c,n] fp16.
// blocks 6144..6161: W fp32 -> fp16.
__global__ __launch_bounds__(256) void k_prep(const float* __restrict__ x,
                                              const float* __restrict__ W,
                                              unsigned short* __restrict__ xt,
                                              unsigned short* __restrict__ xc,
                                              unsigned short* __restrict__ Wb) {
    int bid = blockIdx.x;
    int tid = threadIdx.x;

    if (bid >= 6144) {
        int base = ((bid - 6144) * 256 + tid) * 16;
        union { unsigned short u[16]; uvec4 v[2]; } o;
#pragma unroll
        for (int q = 0; q < 16; q += 4) {
            fvec4 f = __builtin_nontemporal_load((const fvec4*)(W + base + q));
            union { _Float16 h; unsigned short s; } c;
            c.h = (_Float16)f.x; o.u[q + 0] = c.s;
            c.h = (_Float16)f.y; o.u[q + 1] = c.s;
            c.h = (_Float16)f.z; o.u[q + 2] = c.s;
            c.h = (_Float16)f.w; o.u[q + 3] = c.s;
        }
        *(uvec4*)(Wb + base)     = o.v[0];
        *(uvec4*)(Wb + base + 8) = o.v[1];
        return;
    }

    __shared__ float tile[32][33];
    int xcd  = bid & 7;
    int b    = xcd >> 1;
    int half = xcd & 1;
    int slot = bid >> 3;
    int ct   = slot >> 7;
    int nt   = half * 128 + (slot & 127);
    int c0 = ct * 32, n0 = nt * 32;

    int cc  = tid >> 3;
    int nn4 = (tid & 7) * 4;
    const float* xp = x + ((size_t)b * C_ + c0 + cc) * N_ + n0 + nn4;
    fvec4 v = __builtin_nontemporal_load((const fvec4*)xp);

    // xc[b, c, n] fp16 passthrough (same addressing as source, no transpose)
    {
        union { _Float16 h[4]; uvec2 u; } pc;
        pc.h[0] = (_Float16)v.x;
        pc.h[1] = (_Float16)v.y;
        pc.h[2] = (_Float16)v.z;
        pc.h[3] = (_Float16)v.w;
        *(uvec2*)(xc + ((size_t)b * C_ + c0 + cc) * N_ + n0 + nn4) = pc.u;
    }

    tile[nn4 + 0][cc] = v.x;
    tile[nn4 + 1][cc] = v.y;
    tile[nn4 + 2][cc] = v.z;
    tile[nn4 + 3][cc] = v.w;
    __syncthreads();

#pragma unroll
    for (int i = 0; i < 2; i++) {
        int id  = i * 256 + tid;
        int row = id >> 4;
        int ch2 = id & 15;
        union { _Float16 h[2]; unsigned int u; } p;
        p.h[0] = (_Float16)tile[row][ch2 * 2];
        p.h[1] = (_Float16)tile[row][ch2 * 2 + 1];
        *(unsigned int*)(xt + ((size_t)b * N_ + n0 + row) * C_ + c0 + ch2 * 2) = p.u;
    }
}

// ---------------- KG: channel-sliced LDS gather ----------------
// 768 blocks x 256 thr. Block = (batch b, 4-ch slice s, 2048-node quarter nq).
// Stage x[b, slice, all N] into 64 KiB LDS (2 planes of packed half2,
// bank = n%32 -> ~2-way conflicts). Gather via ds_read_b32 pairs, packed
// fp16 max-reduce over k, write rel 8 B per node. eidx streams from L2.
__global__ __launch_bounds__(256) void k_gather(const unsigned short* __restrict__ xc,
                                                const int* __restrict__ eidx,
                                                unsigned short* __restrict__ rt) {
    __shared__ unsigned int lds[2 * N_];   // 64 KiB: plane p at p*N_

    int bid  = blockIdx.x;               // 768
    int xcd  = bid & 7;
    int b    = xcd >> 1;
    int hq   = xcd & 1;                  // n-half (XCD-pins eidx range)
    int rest = bid >> 3;                 // 0..95
    int s    = rest >> 1;                // 0..47
    int qq   = rest & 1;
    int nq   = hq * 2 + qq;              // n-quarter 0..3
    int c0   = s * 4;
    int nbase = nq * 2048;
    int tid  = threadIdx.x;

    // ---- stage 2 planes: plane p <- rows (c0+2p, c0+2p+1) interleaved per node ----
#pragma unroll
    for (int p = 0; p < 2; p++) {
        const unsigned short* ra = xc + ((size_t)b * C_ + c0 + 2 * p) * N_;
        const unsigned short* rb = ra + N_;
#pragma unroll
        for (int i = 0; i < 4; i++) {
            int n0 = i * 2048 + tid * 8;
            uvec4 A = *(const uvec4*)(ra + n0);
            uvec4 Bv = *(const uvec4*)(rb + n0);
#pragma unroll
            for (int q = 0; q < 4; q++) {
                unsigned a = A[q], bb = Bv[q];
                unsigned lo = (a & 0xffffu) | (bb << 16);
                unsigned hi = (a >> 16) | (bb & 0xffff0000u);
                uvec2 w2 = {lo, hi};
                *(uvec2*)&lds[p * N_ + n0 + q * 2] = w2;
            }
        }
    }
    __syncthreads();

    const int* e0 = eidx + (size_t)b * N_ * K_;
    const int* e1 = e0 + (size_t)BN_ * K_;
    unsigned short* rto = rt + (size_t)b * N_ * C_ + c0;

#pragma unroll 2
    for (int i = 0; i < 8; i++) {
        int n = nbase + i * 256 + tid;
        ivec4 J[4], I[4];
#pragma unroll
        for (int kq = 0; kq < 4; kq++) {
            J[kq] = *(const ivec4*)(e0 + (size_t)n * K_ + kq * 4);
            I[kq] = *(const ivec4*)(e1 + (size_t)n * K_ + kq * 4);
        }
        half2v m0 = {(_Float16)-65504.f, (_Float16)-65504.f};
        half2v m1 = m0;
#pragma unroll
        for (int kq = 0; kq < 4; kq++)
#pragma unroll
            for (int e = 0; e < 4; e++) {
                int jn  = J[kq][e];
                int in_ = I[kq][e];
                union { unsigned u; half2v h; } j0, j1, i0, i1;
                j0.u = lds[jn];        j1.u = lds[N_ + jn];
                i0.u = lds[in_];       i1.u = lds[N_ + in_];
                m0 = __builtin_elementwise_max(m0, j0.h - i0.h);
                m1 = __builtin_elementwise_max(m1, j1.h - i1.h);
            }
        union { half2v h; unsigned u; } o0, o1;
        o0.h = m0; o1.h = m1;
        uvec2 ov = {o0.u, o1.u};
        *(uvec2*)(rto + (size_t)n * C_) = ov;
    }
}

// ---------------- KC: 1x1 conv GEMM (fp16 MFMA), swizzled LDS y-tile ----------------
// 512 blocks x 4 waves; block = 64 nodes. ytile[64][384] fp16 (48 KiB),
// XOR-swizzle byte^((row&7)<<4) kills stride-768 bank conflicts.
__global__ __launch_bounds__(256) void k_conv(const unsigned short* __restrict__ xt,
                                              const unsigned short* __restrict__ rt,
                                              const unsigned short* __restrict__ Wb,
                                              const float* __restrict__ bias,
                                              float* __restrict__ out) {
    __shared__ __align__(16) unsigned short ytile[64 * TWOC_];   // 48 KiB
    char* yb = (char*)ytile;

    int bid  = blockIdx.x;               // 512
    int xcd  = bid & 7;
    int b    = xcd >> 1;
    int slot = bid >> 3;                 // 0..63
    int n0   = ((xcd & 1) * 64 + slot) * 64;

    int tid  = threadIdx.x;
    int wave = tid >> 6;
    int lane = tid & 63;
    int m16  = lane & 15;
    int quad = lane >> 4;

    const unsigned short* xsrc = xt + ((size_t)b * N_ + n0) * C_;
    const unsigned short* rsrc = rt + ((size_t)b * N_ + n0) * C_;
#pragma unroll
    for (int i = 0; i < 6; i++) {
        int id = i * 256 + tid;          // 0..1535
        int row = id / 24, chunk = id % 24;
        int sw = (row & 7) << 4;
        half8 vx = *(const half8*)(xsrc + (size_t)row * C_ + chunk * 8);
        half8 vr = *(const half8*)(rsrc + (size_t)row * C_ + chunk * 8);
        *(half8*)(yb + row * 768 + ((chunk * 16) ^ sw))       = vx;
        *(half8*)(yb + row * 768 + 384 + ((chunk * 16) ^ sw)) = vr;
    }
    __syncthreads();

    const unsigned short* wbase = Wb + (size_t)(wave * 48 + m16) * TWOC_ + quad * 8;

    floatx4 acc[3][4];
#pragma unroll
    for (int i = 0; i < 3; i++)
#pragma unroll
        for (int j = 0; j < 4; j++) acc[i][j] = (floatx4){0.f, 0.f, 0.f, 0.f};

#pragma unroll 2
    for (int kt = 0; kt < 12; kt++) {
        half8 wf[3], yf[4];
#pragma unroll
        for (int i = 0; i < 3; i++)
            wf[i] = *(const half8*)(wbase + (size_t)(i * 16) * TWOC_ + kt * 32);
#pragma unroll
        for (int j = 0; j < 4; j++) {
            int row = j * 16 + m16;
            yf[j] = *(const half8*)(yb + row * 768 + ((kt * 64 + quad * 16) ^ ((row & 7) << 4)));
        }
#pragma unroll
        for (int i = 0; i < 3; i++)
#pragma unroll
            for (int j = 0; j < 4; j++)
                acc[i][j] = __builtin_amdgcn_mfma_f32_16x16x32_f16(wf[i], yf[j], acc[i][j], 0, 0, 0);
    }

#pragma unroll
    for (int i = 0; i < 3; i++) {
#pragma unroll
        for (int r = 0; r < 4; r++) {
            int o = wave * 48 + i * 16 + quad * 4 + r;
            float bv = bias[o];
#pragma unroll
            for (int j = 0; j < 4; j++) {
                int n = n0 + j * 16 + m16;
                __builtin_nontemporal_store(fmaxf(acc[i][j][r] + bv, 0.f),
                                            &out[((size_t)b * O_ + o) * N_ + n]);
            }
        }
    }
}

extern "C" void kernel_launch(void* const* d_in, const int* in_sizes, int n_in,
                              void* d_out, int out_size, void* d_ws, size_t ws_size,
                              hipStream_t stream) {
    const float* x    = (const float*)d_in[0];
    const int*   eidx = (const int*)d_in[2];
    const float* W    = (const float*)d_in[3];
    const float* bias = (const float*)d_in[4];
    float*       out  = (float*)d_out;

    unsigned short* Wb = (unsigned short*)d_ws;                       // 147456 B
    unsigned short* xt = (unsigned short*)((char*)d_ws + 147456);     // 12.58 MB  [b,n,c]
    unsigned short* xc = (unsigned short*)((char*)d_ws + 12730368);   // 12.58 MB  [b,c,n]
    unsigned short* rt = (unsigned short*)((char*)d_ws + 25313280);   // 12.58 MB  [b,n,c]

    k_prep<<<dim3(6162), dim3(256), 0, stream>>>(x, W, xt, xc, Wb);
    k_gather<<<dim3(768), dim3(256), 0, stream>>>(xc, eidx, rt);
    k_conv<<<dim3(512), dim3(256), 0, stream>>>(xt, rt, Wb, bias, out);
}